// Round 10
// baseline (559.609 us; speedup 1.0000x reference)
//
#include <hip/hip_runtime.h>

#define BB 4
#define HH 352
#define WW 1216
#define HW (HH * WW)
#define NPIX (BB * HW)   // 1,712,128
#define TX 4             // pixels per thread in conv kernels

// Padded propagation buffer. R18 fused pairs need 2-hop halo:
// rows [y0-8, y0+16] -> PAD_T=PAD_B=9; cols [x0-8, x0+75] -> PAD_L=8, PAD_R=12.
#define PAD_T 9
#define PAD_L 8
#define HP (HH + 2 * 9)          // 370
#define WP (WW + 8 + 12)         // 1236
#define HWP (HP * WP)            // 457,320

// Fused-pair LDS tiles: src 25x84 (2-hop halo), intermediate 17x76.
#define SROWS 25
#define SCOLS 84
#define SSIZE (SROWS * SCOLS)    // 2100
#define IROWS 17
#define ICOLS 76
#define ISIZE (IROWS * ICOLS)    // 1292
#define NTILES 3344              // (WW/64) * (HH/8) * BB

// AoS tap table (R14): one 48B record per px, 16B-aligned:
//   u32 slot 0..7 : packed coords, q=round((rel+4)*8192), y lo16, x hi16,
//                   neighbor order n=0..7 (tap k = n<4 ? n : n+1).
//   u32 slot 8..11: 8 affinities u16 (taps 0,1,2,3,5,6,7,8), q=(a+1)*20000.
// Center-tap affinity reconstructed: ak4 = 1 - sum(others) (TGASS identity).
//
// NOTES carried forward:
//  R3: every loop indexing a register array MUST be fully unrolled.
//  R5: WRITE_SIZE includes harness 0xAA-poison writeback (attribution moves
//      between dispatches run-to-run; R9 conv "144 vs 116" was this).
//  R7: prop NOT byte-bound. R8: LDS tiles + ds_read2_b32.
//  R9/R10/R13: merged 24-out conv DEAD END (AGPR demotion at >32-float acc).
//  R11/R15: 2-role fused conv, flattened 256-thr blocks. KEEP.
//  R14: 48B AoS tap records. R16: coop prop 5x REGRESSION, but PMC: prop is
//      latency-stalled (VALUBusy 7.7% @ 98.8% occ), tab refetched each step.
//  R17: 2-tile pipelined prop + LDS-only barriers (lgkmcnt + raw s_barrier):
//      20.2 us/step. Prop floor ~11-13 (17 LDS instr/px structural).
//  R18 (this round): fuse step PAIRS through LDS. tab is step-invariant, so
//      stage 25x84 src, compute 17x76 intermediate (step 2i, x conf, OOB px
//      = 0 = apron) in LDS, barrier, final 64x8 (step 2i+1) with the SAME
//      ys = fy + q/8192 formula. 18 launches -> 9; feat round-trips halve;
//      intermediate never touches global. Bit-identical op order.

// ---------------------------------------------------------------------------
// Kernel A (role-fused, flattened): grid 3344 = 8 XCDs x 209 blk-pairs.
// Unchanged from R7/R15. Channel mapping (R2): neighbor n: dy=ch[2n],
// dx=ch[2n+1]; aff pre-act = ch[16+n].
// ---------------------------------------------------------------------------
__global__ __launch_bounds__(256) void conv_fused_kernel(
    const float* __restrict__ guid, const float* __restrict__ w,
    const float* __restrict__ bias, const float* __restrict__ scale_p,
    unsigned* __restrict__ tab)
{
    int tid = threadIdx.x;
    int bid = blockIdx.x;                  // 0..3343
    int xcd = bid & 7;
    int u = bid >> 3;                      // 0..417
    int role = u & 1;                      // block-uniform
    int blk = xcd * 209 + (u >> 1);        // 0..1671
    int gg = blk * 256 + tid;              // 4-px group id, 0..428031
    int row = gg / 304;                    // 0..1407
    int x0 = (gg % 304) * TX;
    int y = row % HH;
    int b = row / HH;
    const float* gb = guid + (size_t)b * 8 * HW;

    if (role == 0) {
        float acc[16][TX];
#pragma unroll
        for (int o = 0; o < 16; ++o) {
            float bv = bias[o];
#pragma unroll
            for (int tx = 0; tx < TX; ++tx) acc[o][tx] = bv;
        }

#pragma unroll 1
        for (int c = 0; c < 8; ++c) {
            float g[3][6];
#pragma unroll
            for (int r = 0; r < 3; ++r) {
                int yy = y + r - 1;
                bool rv = (yy >= 0) && (yy < HH);
                const float* gr = gb + (size_t)c * HW + (size_t)yy * WW;
                if (rv) {
                    const float4 m = *(const float4*)(gr + x0);
                    g[r][1] = m.x; g[r][2] = m.y; g[r][3] = m.z; g[r][4] = m.w;
                    g[r][0] = (x0 > 0) ? gr[x0 - 1] : 0.f;
                    g[r][5] = (x0 + TX < WW) ? gr[x0 + TX] : 0.f;
                } else {
#pragma unroll
                    for (int i = 0; i < 6; ++i) g[r][i] = 0.f;
                }
            }
#pragma unroll
            for (int r = 0; r < 3; ++r) {
#pragma unroll
                for (int i = 0; i < 3; ++i) {
                    int tap = r * 3 + i;
#pragma unroll
                    for (int o = 0; o < 16; ++o) {
                        float wv = w[o * 72 + c * 9 + tap];  // uniform -> s_load
#pragma unroll
                        for (int tx = 0; tx < TX; ++tx)
                            acc[o][tx] = fmaf(wv, g[r][i + tx], acc[o][tx]);
                    }
                }
            }
        }

        int idx0 = row * WW + x0;
#pragma unroll
        for (int tx = 0; tx < TX; ++tx) {
            unsigned cw8[8];
#pragma unroll
            for (int n = 0; n < 8; ++n) {
                int k = (n < 4) ? n : n + 1;
                float ky = (float)(k / 3 - 1), kx = (float)(k % 3 - 1);
                float yr = ky + acc[2 * n][tx];
                float xr = kx + acc[2 * n + 1][tx];
                int yq = (int)lrintf((yr + 4.f) * 8192.f);
                int xq = (int)lrintf((xr + 4.f) * 8192.f);
                yq = min(max(yq, 0), 65535);
                xq = min(max(xq, 0), 65535);
                cw8[n] = (unsigned)yq | ((unsigned)xq << 16);
            }
            unsigned* tp = tab + (size_t)(idx0 + tx) * 12;
            *(uint4*)(tp)     = make_uint4(cw8[0], cw8[1], cw8[2], cw8[3]);
            *(uint4*)(tp + 4) = make_uint4(cw8[4], cw8[5], cw8[6], cw8[7]);
        }
    } else {
        float acc[8][TX];
#pragma unroll
        for (int o = 0; o < 8; ++o) {
            float bv = bias[16 + o];
#pragma unroll
            for (int tx = 0; tx < TX; ++tx) acc[o][tx] = bv;
        }

#pragma unroll 1
        for (int c = 0; c < 8; ++c) {
            float g[3][6];
#pragma unroll
            for (int r = 0; r < 3; ++r) {
                int yy = y + r - 1;
                bool rv = (yy >= 0) && (yy < HH);
                const float* gr = gb + (size_t)c * HW + (size_t)yy * WW;
                if (rv) {
                    const float4 m = *(const float4*)(gr + x0);
                    g[r][1] = m.x; g[r][2] = m.y; g[r][3] = m.z; g[r][4] = m.w;
                    g[r][0] = (x0 > 0) ? gr[x0 - 1] : 0.f;
                    g[r][5] = (x0 + TX < WW) ? gr[x0 + TX] : 0.f;
                } else {
#pragma unroll
                    for (int i = 0; i < 6; ++i) g[r][i] = 0.f;
                }
            }
#pragma unroll
            for (int r = 0; r < 3; ++r) {
#pragma unroll
                for (int i = 0; i < 3; ++i) {
                    int tap = r * 3 + i;
#pragma unroll
                    for (int o = 0; o < 8; ++o) {
                        float wv = w[(16 + o) * 72 + c * 9 + tap];
#pragma unroll
                        for (int tx = 0; tx < TX; ++tx)
                            acc[o][tx] = fmaf(wv, g[r][i + tx], acc[o][tx]);
                    }
                }
            }
        }

        float sc = scale_p[0] + 1e-8f;
        int idx0 = row * WW + x0;
#pragma unroll
        for (int tx = 0; tx < TX; ++tx) {
            float a[8];
            float asum = 1e-4f;
#pragma unroll
            for (int n = 0; n < 8; ++n) {
                a[n] = tanhf(acc[n][tx]) / sc;
                asum += fabsf(a[n]);
            }
            asum = fmaxf(asum, 1.0f);
            unsigned q8[8];
#pragma unroll
            for (int n = 0; n < 8; ++n) {
                a[n] = a[n] / asum;
                int q = (int)lrintf((a[n] + 1.f) * 20000.f);
                q = min(max(q, 0), 65535);
                q8[n] = (unsigned)q;
            }
            unsigned* tp = tab + (size_t)(idx0 + tx) * 12 + 8;
            *(uint4*)(tp) = make_uint4(q8[0] | (q8[1] << 16), q8[2] | (q8[3] << 16),
                                       q8[4] | (q8[5] << 16), q8[6] | (q8[7] << 16));
        }
    }
}

// ---------------------------------------------------------------------------
// Shared 9-tap DCN sample at (fy + q/8192, fx + q/8192) from tile T.
// Identical op order to the R8-R17 prop body (bit-identical results).
// ---------------------------------------------------------------------------
template <int STRIDE>
__device__ __forceinline__ float dcn_px(const float* __restrict__ T,
    float fy, float fx, uint4 t0, uint4 t1, uint4 t2)
{
    unsigned cw[8] = {t0.x, t0.y, t0.z, t0.w, t1.x, t1.y, t1.z, t1.w};
    float ak[9];
    ak[0] = fmaf((float)(t2.x & 0xffffu), 5e-5f, -1.f);
    ak[1] = fmaf((float)(t2.x >> 16),     5e-5f, -1.f);
    ak[2] = fmaf((float)(t2.y & 0xffffu), 5e-5f, -1.f);
    ak[3] = fmaf((float)(t2.y >> 16),     5e-5f, -1.f);
    ak[5] = fmaf((float)(t2.z & 0xffffu), 5e-5f, -1.f);
    ak[6] = fmaf((float)(t2.z >> 16),     5e-5f, -1.f);
    ak[7] = fmaf((float)(t2.w & 0xffffu), 5e-5f, -1.f);
    ak[8] = fmaf((float)(t2.w >> 16),     5e-5f, -1.f);
    ak[4] = 1.f - (((ak[0] + ak[1]) + (ak[2] + ak[3]))
                 + ((ak[5] + ak[6]) + (ak[7] + ak[8])));

    float res = ak[4] * T[((int)fy + 4) * STRIDE + (int)fx + 4];  // exact center
#pragma unroll
    for (int n = 0; n < 8; ++n) {
        float ys = fmaf((float)(cw[n] & 0xffffu), 1.f / 8192.f, fy);
        float xs = fmaf((float)(cw[n] >> 16),     1.f / 8192.f, fx);
        float y0f = floorf(ys), x0f = floorf(xs);
        float wy1 = ys - y0f, wx1 = xs - x0f;
        float wy0 = 1.f - wy1, wx0 = 1.f - wx1;
        int o = (int)y0f * STRIDE + (int)x0f;
        float v00 = T[o],          v01 = T[o + 1];           // ds_read2
        float v10 = T[o + STRIDE], v11 = T[o + STRIDE + 1];  // ds_read2
        float sv = wy0 * (wx0 * v00 + wx1 * v01) + wy1 * (wx0 * v10 + wx1 * v11);
        int k = (n < 4) ? n : n + 1;
        res = fmaf(ak[k], sv, res);
    }
    return res;
}

// ---------------------------------------------------------------------------
// Kernel B (R18): TWO propagation steps fused through LDS.
// Block = 512 thr, one 64x8 output tile; grid 3344, XCD slab mapping (R7).
// Phase 1: stage src 25x84 (2-hop halo) from padded buffer.
// Phase 2: intermediate 17x76 = step-2i output x conf; 3 masked 512-slots;
//          out-of-image px -> 0 (apron semantics). ys = pr + q/8192.
// Phase 3: final 64x8 = step-2i+1 from intermediate; ys = ly + q/8192.
// Barriers are LDS-only (lgkmcnt + raw s_barrier) so tab loads issued for
// later phases stay in flight (R17 pattern, verified passing).
// ---------------------------------------------------------------------------
template <bool LAST>
__global__ __launch_bounds__(512) void prop_pair_kernel(
    const float* __restrict__ fsrc, const unsigned* __restrict__ tab,
    const float* __restrict__ conf, float* __restrict__ dst)
{
    __shared__ float S[SSIZE];
    __shared__ float I[ISIZE];

    int bid = blockIdx.x;                 // 0..3343
    int gid = (bid & 7) * 418 + (bid >> 3);
    int b = gid / 836;                    // 836 = 19 * 44 tiles per image
    int r2 = gid % 836;
    int yband = r2 / 19;                  // 0..43
    int xb = r2 % 19;                     // 0..18
    int y0 = yband * 8, x0 = xb * 64;
    int t = threadIdx.x;
    int lx = t & 63, ly = t >> 6;         // ly 0..7

    // ---- issue src staging loads (rows [y0-8,y0+16], cols [x0-8,x0+75]) --
    // padded row (y0-8)+PAD_T = y0+1; padded col (x0-8)+PAD_L = x0.
    const float* gs = fsrc + (size_t)b * HWP + (size_t)(y0 + 1) * WP + x0;
    float s0 = gs[(t) / SCOLS * WP + (t) % SCOLS];
    float s1 = gs[(t + 512) / SCOLS * WP + (t + 512) % SCOLS];
    float s2 = gs[(t + 1024) / SCOLS * WP + (t + 1024) % SCOLS];
    float s3 = gs[(t + 1536) / SCOLS * WP + (t + 1536) % SCOLS];
    float s4 = (t + 2048 < SSIZE)
             ? gs[(t + 2048) / SCOLS * WP + (t + 2048) % SCOLS] : 0.f;

    // ---- slot 0/1 tab+conf loads (predicated by in-image) ----------------
    auto tload = [&](int p, uint4& c0, uint4& c1, uint4& c2, float& cf,
                     bool& valid, int& pr, int& pc) {
        pr = p / ICOLS; pc = p % ICOLS;
        int yi = y0 - 4 + pr, xi = x0 - 4 + pc;
        valid = (p < ISIZE) && (yi >= 0) && (yi < HH) && (xi >= 0) && (xi < WW);
        if (valid) {
            int idx = (b * HH + yi) * WW + xi;
            const unsigned* tp = tab + (size_t)idx * 12;
            c0 = *(const uint4*)(tp);
            c1 = *(const uint4*)(tp + 4);
            c2 = *(const uint4*)(tp + 8);
            cf = conf[idx];
        } else {
            c0 = c1 = c2 = make_uint4(0u, 0u, 0u, 0u);
            cf = 0.f;
        }
    };

    uint4 c00, c01, c02, c10, c11, c12;
    float cf0, cf1;
    bool v0, v1;
    int pr0, pc0, pr1, pc1;
    tload(t, c00, c01, c02, cf0, v0, pr0, pc0);
    tload(t + 512, c10, c11, c12, cf1, v1, pr1, pc1);

    // ---- write src tile to LDS (compiler inserts vmcnt waits on s*) ------
    S[t] = s0;
    S[t + 512] = s1;
    S[t + 1024] = s2;
    S[t + 1536] = s3;
    if (t + 2048 < SSIZE) S[t + 2048] = s4;

    // ---- issue slot2 + final tab loads; they fly across barrier 1 --------
    uint4 c20, c21, c22;
    float cf2;
    bool v2;
    int pr2, pc2;
    tload(t + 1024, c20, c21, c22, cf2, v2, pr2, pc2);

    int yF = y0 + ly, xF = x0 + lx;
    int idxF = (b * HH + yF) * WW + xF;
    const unsigned* tpF = tab + (size_t)idxF * 12;
    uint4 f0 = *(const uint4*)(tpF);
    uint4 f1 = *(const uint4*)(tpF + 4);
    uint4 f2 = *(const uint4*)(tpF + 8);
    float cvF = LAST ? 0.f : conf[idxF];

    // ---- barrier 1: LDS drain only (tab loads stay outstanding) ----------
    asm volatile("s_waitcnt lgkmcnt(0)" ::: "memory");
    __builtin_amdgcn_s_barrier();
    __builtin_amdgcn_sched_barrier(0);

    // ---- phase 2: intermediate = conf * dcn(src), OOB -> 0 ---------------
    {
        float vI = 0.f;
        if (v0) vI = cf0 * dcn_px<SCOLS>(S, (float)pr0, (float)pc0, c00, c01, c02);
        I[t] = vI;                         // p = t < 1292 always
    }
    {
        float vI = 0.f;
        if (v1) vI = cf1 * dcn_px<SCOLS>(S, (float)pr1, (float)pc1, c10, c11, c12);
        I[t + 512] = vI;                   // p < 1024 < 1292 always
    }
    if (t + 1024 < ISIZE) {
        float vI = 0.f;
        if (v2) vI = cf2 * dcn_px<SCOLS>(S, (float)pr2, (float)pc2, c20, c21, c22);
        I[t + 1024] = vI;
    }

    // ---- barrier 2: LDS drain only ---------------------------------------
    asm volatile("s_waitcnt lgkmcnt(0)" ::: "memory");
    __builtin_amdgcn_s_barrier();
    __builtin_amdgcn_sched_barrier(0);

    // ---- phase 3: final from intermediate --------------------------------
    float res = dcn_px<ICOLS>(I, (float)ly, (float)lx, f0, f1, f2);
    if (LAST) {
        dst[idxF] = res;                   // dst == out, unpadded
    } else {
        dst[(size_t)b * HWP + (yF + PAD_T) * WP + (xF + PAD_L)] = res * cvF;
    }
}

// Zero both padded buffers (apron must be 0; ws is poisoned 0xAA each launch).
__global__ __launch_bounds__(256) void zero_kernel(float4* __restrict__ p, int n4)
{
    int i = blockIdx.x * blockDim.x + threadIdx.x;
    if (i < n4) p[i] = make_float4(0.f, 0.f, 0.f, 0.f);
}

// fc0[padded interior] = feat_init * conf
__global__ __launch_bounds__(256) void mulpad_kernel(
    const float* __restrict__ a, const float* __restrict__ c, float* __restrict__ o)
{
    int t = threadIdx.x;
    int x = blockIdx.x * 64 + (t & 63);
    int y = blockIdx.y * 4 + (t >> 6);
    int b = blockIdx.z;
    int idx = (b * HH + y) * WW + x;
    o[(size_t)b * HWP + (y + PAD_T) * WP + (x + PAD_L)] = a[idx] * c[idx];
}

extern "C" void kernel_launch(void* const* d_in, const int* in_sizes, int n_in,
                              void* d_out, int out_size, void* d_ws, size_t ws_size,
                              hipStream_t stream)
{
    const float* feat_init  = (const float*)d_in[0];
    const float* guidance   = (const float*)d_in[1];
    const float* confidence = (const float*)d_in[2];
    const float* w_oa       = (const float*)d_in[3];
    const float* b_oa       = (const float*)d_in[4];
    const float* aff_scale  = (const float*)d_in[5];
    float* out = (float*)d_out;

    // Workspace: tab u32[12N] (82.2 MB) | fc0p f32[BB*HWP] | fc1p  (96.9 MB)
    const size_t N = (size_t)NPIX;
    unsigned* tab = (unsigned*)d_ws;
    float* fc0 = (float*)(tab + 12 * N);
    float* fc1 = fc0 + (size_t)BB * HWP;

    const dim3 mgrid(WW / 64, HH / 4, BB);
    const int n4 = 2 * BB * HWP / 4;
    zero_kernel<<<(n4 + 255) / 256, 256, 0, stream>>>((float4*)fc0, n4);
    mulpad_kernel<<<mgrid, 256, 0, stream>>>(feat_init, confidence, fc0);
    conv_fused_kernel<<<2 * 1672, 256, 0, stream>>>(
        guidance, w_oa, b_oa, aff_scale, tab);

    // 9 fused pairs (= 18 steps). Pair p reads bufs[p&1], writes bufs[(p+1)&1].
    float* bufs[2] = {fc0, fc1};
    for (int p = 0; p < 9; ++p) {
        const float* src = bufs[p & 1];
        if (p < 8) {
            float* dst = bufs[(p + 1) & 1];
            prop_pair_kernel<false><<<NTILES, 512, 0, stream>>>(
                src, tab, confidence, dst);
        } else {
            prop_pair_kernel<true><<<NTILES, 512, 0, stream>>>(
                src, tab, confidence, out);
        }
    }
}

// Round 11
// 512.195 us; speedup vs baseline: 1.0926x; 1.0926x over previous
//
#include <hip/hip_runtime.h>

#define BB 4
#define HH 352
#define WW 1216
#define HW (HH * WW)
#define NPIX (BB * HW)   // 1,712,128
#define TX 4             // pixels per thread in conv kernels

// Padded propagation buffer: apron of zeros so bilinear gathers need no
// bounds checks. |rel| <= 4 (encode clamp) => corners in [y-4,y+5]x[x-4,x+5].
#define PAD_T 5
#define PAD_L 8
#define HP (HH + 2 * PAD_T)      // 362
#define WP (WW + 2 * PAD_L)      // 1232 (divisible by 4 -> float4 init)
#define HWP (HP * WP)            // 445,984

// Prop LDS tile (R15): block covers 64x8 px; samples live in rows [0,15],
// cols [0,71]; stage 17 x 76 (stride 76: banks shift 12/row, ~2 lanes/bank).
#define TROWS 17
#define TCOLS 76
#define TSIZE (TROWS * TCOLS)    // 1292
#define NTILES 3344              // (WW/64) * (HH/8) * BB

// AoS tap table (R14): one 48B record per px, 16B-aligned:
//   u32 slot 0..7 : packed coords, q=round((rel+4)*8192), y lo16, x hi16,
//                   neighbor order n=0..7 (tap k = n<4 ? n : n+1).
//   u32 slot 8..11: 8 affinities u16 (taps 0,1,2,3,5,6,7,8), q=(a+1)*20000.
// Center-tap affinity reconstructed: ak4 = 1 - sum(others) (TGASS identity).
//
// NOTES carried forward:
//  R3: every loop indexing a register array MUST be fully unrolled.
//  R5: WRITE_SIZE includes harness 0xAA-poison writeback (attribution moves
//      between dispatches run-to-run).
//  R7: prop NOT byte-bound. R8: LDS tiles + ds_read2_b32.
//  R9/R10/R13: merged 24-out conv DEAD END (AGPR demotion at >32-float acc).
//  R11/R15: 2-role fused conv, flattened 256-thr blocks = ~117 us. KEEP.
//  R14: 48B AoS tap records (579.6 -> 558.3).
//  R16: coop 18-step prop = 5x REGRESSION. PMC: prop latency-stalled
//      (VALUBusy 7.7% @ 98.8% occ), tab refetched from HBM each step.
//  R17: 2-tile pipelined prop, LDS-only barriers (lgkmcnt + raw s_barrier):
//      20.2 us/step. BEST prop. KEEP.
//  R18: pair-fusion REGRESSED (48.2 us/pair vs 40.4): 2.52x intermediate
//      redundancy + 1.76x tab loads at 64x8 tiles. Structure abandoned.
//  R19 (this round): revert to R17 prop + R15 conv; fold zero+mulpad into
//      one init_kernel (one launch, single write of fc0 interior).

// ---------------------------------------------------------------------------
// Kernel A (role-fused, flattened): grid 3344 = 8 XCDs x 209 blk-pairs.
//   xcd = bid&7, u = bid>>3, role = u&1, blk = xcd*209 + (u>>1).
// Each block: 256 threads x one 4-px group; group gg = blk*256+tid;
// row = gg/304, x0 = (gg%304)*4.  428,032 groups = 1672 blocks exactly.
// role 0: ch 0..15 -> coord slots 0..7. role 1: ch 16..23 + TGASS -> 8..11.
// Channel mapping (verified R2): neighbor n: dy = ch[2n], dx = ch[2n+1].
// ---------------------------------------------------------------------------
__global__ __launch_bounds__(256) void conv_fused_kernel(
    const float* __restrict__ guid, const float* __restrict__ w,
    const float* __restrict__ bias, const float* __restrict__ scale_p,
    unsigned* __restrict__ tab)
{
    int tid = threadIdx.x;
    int bid = blockIdx.x;                  // 0..3343
    int xcd = bid & 7;
    int u = bid >> 3;                      // 0..417
    int role = u & 1;                      // block-uniform
    int blk = xcd * 209 + (u >> 1);        // 0..1671
    int gg = blk * 256 + tid;              // 4-px group id, 0..428031
    int row = gg / 304;                    // 0..1407
    int x0 = (gg % 304) * TX;
    int y = row % HH;
    int b = row / HH;
    const float* gb = guid + (size_t)b * 8 * HW;

    if (role == 0) {
        float acc[16][TX];
#pragma unroll
        for (int o = 0; o < 16; ++o) {
            float bv = bias[o];
#pragma unroll
            for (int tx = 0; tx < TX; ++tx) acc[o][tx] = bv;
        }

#pragma unroll 1
        for (int c = 0; c < 8; ++c) {
            float g[3][6];
#pragma unroll
            for (int r = 0; r < 3; ++r) {
                int yy = y + r - 1;
                bool rv = (yy >= 0) && (yy < HH);
                const float* gr = gb + (size_t)c * HW + (size_t)yy * WW;
                if (rv) {
                    const float4 m = *(const float4*)(gr + x0);
                    g[r][1] = m.x; g[r][2] = m.y; g[r][3] = m.z; g[r][4] = m.w;
                    g[r][0] = (x0 > 0) ? gr[x0 - 1] : 0.f;
                    g[r][5] = (x0 + TX < WW) ? gr[x0 + TX] : 0.f;
                } else {
#pragma unroll
                    for (int i = 0; i < 6; ++i) g[r][i] = 0.f;
                }
            }
#pragma unroll
            for (int r = 0; r < 3; ++r) {
#pragma unroll
                for (int i = 0; i < 3; ++i) {
                    int tap = r * 3 + i;
#pragma unroll
                    for (int o = 0; o < 16; ++o) {
                        float wv = w[o * 72 + c * 9 + tap];  // uniform -> s_load
#pragma unroll
                        for (int tx = 0; tx < TX; ++tx)
                            acc[o][tx] = fmaf(wv, g[r][i + tx], acc[o][tx]);
                    }
                }
            }
        }

        int idx0 = row * WW + x0;
#pragma unroll
        for (int tx = 0; tx < TX; ++tx) {
            unsigned cw8[8];
#pragma unroll
            for (int n = 0; n < 8; ++n) {
                int k = (n < 4) ? n : n + 1;
                float ky = (float)(k / 3 - 1), kx = (float)(k % 3 - 1);
                float yr = ky + acc[2 * n][tx];
                float xr = kx + acc[2 * n + 1][tx];
                int yq = (int)lrintf((yr + 4.f) * 8192.f);
                int xq = (int)lrintf((xr + 4.f) * 8192.f);
                yq = min(max(yq, 0), 65535);
                xq = min(max(xq, 0), 65535);
                cw8[n] = (unsigned)yq | ((unsigned)xq << 16);
            }
            unsigned* tp = tab + (size_t)(idx0 + tx) * 12;
            *(uint4*)(tp)     = make_uint4(cw8[0], cw8[1], cw8[2], cw8[3]);
            *(uint4*)(tp + 4) = make_uint4(cw8[4], cw8[5], cw8[6], cw8[7]);
        }
    } else {
        float acc[8][TX];
#pragma unroll
        for (int o = 0; o < 8; ++o) {
            float bv = bias[16 + o];
#pragma unroll
            for (int tx = 0; tx < TX; ++tx) acc[o][tx] = bv;
        }

#pragma unroll 1
        for (int c = 0; c < 8; ++c) {
            float g[3][6];
#pragma unroll
            for (int r = 0; r < 3; ++r) {
                int yy = y + r - 1;
                bool rv = (yy >= 0) && (yy < HH);
                const float* gr = gb + (size_t)c * HW + (size_t)yy * WW;
                if (rv) {
                    const float4 m = *(const float4*)(gr + x0);
                    g[r][1] = m.x; g[r][2] = m.y; g[r][3] = m.z; g[r][4] = m.w;
                    g[r][0] = (x0 > 0) ? gr[x0 - 1] : 0.f;
                    g[r][5] = (x0 + TX < WW) ? gr[x0 + TX] : 0.f;
                } else {
#pragma unroll
                    for (int i = 0; i < 6; ++i) g[r][i] = 0.f;
                }
            }
#pragma unroll
            for (int r = 0; r < 3; ++r) {
#pragma unroll
                for (int i = 0; i < 3; ++i) {
                    int tap = r * 3 + i;
#pragma unroll
                    for (int o = 0; o < 8; ++o) {
                        float wv = w[(16 + o) * 72 + c * 9 + tap];
#pragma unroll
                        for (int tx = 0; tx < TX; ++tx)
                            acc[o][tx] = fmaf(wv, g[r][i + tx], acc[o][tx]);
                    }
                }
            }
        }

        float sc = scale_p[0] + 1e-8f;
        int idx0 = row * WW + x0;
#pragma unroll
        for (int tx = 0; tx < TX; ++tx) {
            float a[8];
            float asum = 1e-4f;
#pragma unroll
            for (int n = 0; n < 8; ++n) {
                a[n] = tanhf(acc[n][tx]) / sc;
                asum += fabsf(a[n]);
            }
            asum = fmaxf(asum, 1.0f);
            unsigned q8[8];
#pragma unroll
            for (int n = 0; n < 8; ++n) {
                a[n] = a[n] / asum;
                int q = (int)lrintf((a[n] + 1.f) * 20000.f);
                q = min(max(q, 0), 65535);
                q8[n] = (unsigned)q;
            }
            unsigned* tp = tab + (size_t)(idx0 + tx) * 12 + 8;
            *(uint4*)(tp) = make_uint4(q8[0] | (q8[1] << 16), q8[2] | (q8[3] << 16),
                                       q8[4] | (q8[5] << 16), q8[6] | (q8[7] << 16));
        }
    }
}

// ---------------------------------------------------------------------------
// Kernel B (R17, verified): one prop step, 2 tiles per block, pipelined.
// Grid 1672 = 8 XCDs x 209; tiles gidA = xcd*418 + 2s, gidB = gidA+1 (both
// in the same XCD slab). Stage A -> issue B loads -> LDS-only barrier ->
// compute A (B latency hides) -> LDS-write B -> barrier -> compute B.
// Raw s_barrier + asm lgkmcnt(0) skips __syncthreads' vmcnt(0) drain so
// B's global loads stay in flight across the first barrier.
// ---------------------------------------------------------------------------
template <bool MULCONF>
__global__ __launch_bounds__(512) void prop_step_kernel(
    const float* __restrict__ fsrc, const unsigned* __restrict__ tab,
    const float* __restrict__ conf, float* __restrict__ dst)
{
    __shared__ float tileA[TSIZE];
    __shared__ float tileB[TSIZE];

    int bid = blockIdx.x;                 // 0..1671
    int xcd = bid & 7;
    int s = bid >> 3;                     // 0..208
    int gidA = xcd * 418 + 2 * s;
    int gidB = gidA + 1;
    int t = threadIdx.x;
    int lx = t & 63, ly = t >> 6;         // ly 0..7

    // ---- geometry ----
    int bA = gidA / 836, r2A = gidA % 836;
    int ybA = r2A / 19, xbA = r2A % 19;
    int xA = xbA * 64 + lx, yA = ybA * 8 + ly;
    int idxA = (bA * HH + yA) * WW + xA;

    int bB = gidB / 836, r2B = gidB % 836;
    int ybB = r2B / 19, xbB = r2B % 19;
    int xB = xbB * 64 + lx, yB = ybB * 8 + ly;
    int idxB = (bB * HH + yB) * WW + xB;

    // ---- issue A loads (tab + conf + stage) ----
    const unsigned* tpA = tab + (size_t)idxA * 12;
    uint4 a0 = *(const uint4*)(tpA);
    uint4 a1 = *(const uint4*)(tpA + 4);
    uint4 a2 = *(const uint4*)(tpA + 8);
    float cvA = MULCONF ? conf[idxA] : 0.f;

    const float* gsA = fsrc + (size_t)bA * HWP
                     + (size_t)(ybA * 8 + 1) * WP + (xbA * 64 + 4);
    float rA0 = gsA[(t / TCOLS) * WP + (t % TCOLS)];
    float rA1 = gsA[((t + 512) / TCOLS) * WP + ((t + 512) % TCOLS)];
    float rA2 = (t + 1024 < TSIZE)
              ? gsA[((t + 1024) / TCOLS) * WP + ((t + 1024) % TCOLS)] : 0.f;

    // ---- LDS-write A (compiler inserts vmcnt waits on rA*) ----
    tileA[t] = rA0;
    tileA[t + 512] = rA1;
    if (t + 1024 < TSIZE) tileA[t + 1024] = rA2;

    // ---- issue B loads; they stay outstanding across barrier 1 ----
    const unsigned* tpB = tab + (size_t)idxB * 12;
    uint4 b0 = *(const uint4*)(tpB);
    uint4 b1 = *(const uint4*)(tpB + 4);
    uint4 b2 = *(const uint4*)(tpB + 8);
    float cvB = MULCONF ? conf[idxB] : 0.f;

    const float* gsB = fsrc + (size_t)bB * HWP
                     + (size_t)(ybB * 8 + 1) * WP + (xbB * 64 + 4);
    float rB0 = gsB[(t / TCOLS) * WP + (t % TCOLS)];
    float rB1 = gsB[((t + 512) / TCOLS) * WP + ((t + 512) % TCOLS)];
    float rB2 = (t + 1024 < TSIZE)
              ? gsB[((t + 1024) / TCOLS) * WP + ((t + 1024) % TCOLS)] : 0.f;

    // ---- barrier 1: LDS-only drain (NOT vmcnt) ----
    asm volatile("s_waitcnt lgkmcnt(0)" ::: "memory");
    __builtin_amdgcn_s_barrier();
    __builtin_amdgcn_sched_barrier(0);

    float fy = (float)ly;
    float fx = (float)lx;

    // ---- compute A ----
    {
        unsigned cw[8] = {a0.x, a0.y, a0.z, a0.w, a1.x, a1.y, a1.z, a1.w};
        float ak[9];
        ak[0] = fmaf((float)(a2.x & 0xffffu), 5e-5f, -1.f);
        ak[1] = fmaf((float)(a2.x >> 16),     5e-5f, -1.f);
        ak[2] = fmaf((float)(a2.y & 0xffffu), 5e-5f, -1.f);
        ak[3] = fmaf((float)(a2.y >> 16),     5e-5f, -1.f);
        ak[5] = fmaf((float)(a2.z & 0xffffu), 5e-5f, -1.f);
        ak[6] = fmaf((float)(a2.z >> 16),     5e-5f, -1.f);
        ak[7] = fmaf((float)(a2.w & 0xffffu), 5e-5f, -1.f);
        ak[8] = fmaf((float)(a2.w >> 16),     5e-5f, -1.f);
        ak[4] = 1.f - (((ak[0] + ak[1]) + (ak[2] + ak[3]))
                     + ((ak[5] + ak[6]) + (ak[7] + ak[8])));

        float res = ak[4] * tileA[(ly + 4) * TCOLS + (lx + 4)];
#pragma unroll
        for (int n = 0; n < 8; ++n) {
            float ys = fmaf((float)(cw[n] & 0xffffu), 1.f / 8192.f, fy);
            float xs = fmaf((float)(cw[n] >> 16),     1.f / 8192.f, fx);
            float y0f = floorf(ys), x0f = floorf(xs);
            float wy1 = ys - y0f, wx1 = xs - x0f;
            float wy0 = 1.f - wy1, wx0 = 1.f - wx1;
            int o = (int)y0f * TCOLS + (int)x0f;
            float v00 = tileA[o],         v01 = tileA[o + 1];
            float v10 = tileA[o + TCOLS], v11 = tileA[o + TCOLS + 1];
            float sv = wy0 * (wx0 * v00 + wx1 * v01)
                     + wy1 * (wx0 * v10 + wx1 * v11);
            int k = (n < 4) ? n : n + 1;
            res = fmaf(ak[k], sv, res);
        }
        if (MULCONF)
            dst[(size_t)bA * HWP + (yA + PAD_T) * WP + (xA + PAD_L)] = res * cvA;
        else
            dst[idxA] = res;
    }

    // ---- LDS-write B (rB* arrived during compute A) ----
    tileB[t] = rB0;
    tileB[t + 512] = rB1;
    if (t + 1024 < TSIZE) tileB[t + 1024] = rB2;

    // ---- barrier 2: LDS-only drain ----
    asm volatile("s_waitcnt lgkmcnt(0)" ::: "memory");
    __builtin_amdgcn_s_barrier();
    __builtin_amdgcn_sched_barrier(0);

    // ---- compute B ----
    {
        unsigned cw[8] = {b0.x, b0.y, b0.z, b0.w, b1.x, b1.y, b1.z, b1.w};
        float ak[9];
        ak[0] = fmaf((float)(b2.x & 0xffffu), 5e-5f, -1.f);
        ak[1] = fmaf((float)(b2.x >> 16),     5e-5f, -1.f);
        ak[2] = fmaf((float)(b2.y & 0xffffu), 5e-5f, -1.f);
        ak[3] = fmaf((float)(b2.y >> 16),     5e-5f, -1.f);
        ak[5] = fmaf((float)(b2.z & 0xffffu), 5e-5f, -1.f);
        ak[6] = fmaf((float)(b2.z >> 16),     5e-5f, -1.f);
        ak[7] = fmaf((float)(b2.w & 0xffffu), 5e-5f, -1.f);
        ak[8] = fmaf((float)(b2.w >> 16),     5e-5f, -1.f);
        ak[4] = 1.f - (((ak[0] + ak[1]) + (ak[2] + ak[3]))
                     + ((ak[5] + ak[6]) + (ak[7] + ak[8])));

        float res = ak[4] * tileB[(ly + 4) * TCOLS + (lx + 4)];
#pragma unroll
        for (int n = 0; n < 8; ++n) {
            float ys = fmaf((float)(cw[n] & 0xffffu), 1.f / 8192.f, fy);
            float xs = fmaf((float)(cw[n] >> 16),     1.f / 8192.f, fx);
            float y0f = floorf(ys), x0f = floorf(xs);
            float wy1 = ys - y0f, wx1 = xs - x0f;
            float wy0 = 1.f - wy1, wx0 = 1.f - wx1;
            int o = (int)y0f * TCOLS + (int)x0f;
            float v00 = tileB[o],         v01 = tileB[o + 1];
            float v10 = tileB[o + TCOLS], v11 = tileB[o + TCOLS + 1];
            float sv = wy0 * (wx0 * v00 + wx1 * v01)
                     + wy1 * (wx0 * v10 + wx1 * v11);
            int k = (n < 4) ? n : n + 1;
            res = fmaf(ak[k], sv, res);
        }
        if (MULCONF)
            dst[(size_t)bB * HWP + (yB + PAD_T) * WP + (xB + PAD_L)] = res * cvB;
        else
            dst[idxB] = res;
    }
}

// ---------------------------------------------------------------------------
// init_kernel (R19): one pass over both padded buffers (float4 granular).
// fc0 interior = feat_init * conf; fc0 apron = 0; fc1 = 0 everywhere.
// Interior float4: padded row in [PAD_T, PAD_T+HH), col4 in [2, 305]
// (cols 8..1223 = PAD_L..PAD_L+WW-1; WP/4 = 308).
// ---------------------------------------------------------------------------
__global__ __launch_bounds__(256) void init_kernel(
    const float* __restrict__ feat, const float* __restrict__ conf,
    float4* __restrict__ fc0, float4* __restrict__ fc1)
{
    int i = blockIdx.x * 256 + threadIdx.x;
    const int q = BB * HWP / 4;           // float4s per buffer (445,984)
    if (i >= 2 * q) return;
    if (i >= q) {                          // fc1: all zero
        fc1[i - q] = make_float4(0.f, 0.f, 0.f, 0.f);
        return;
    }
    int b = i / (HWP / 4);
    int p4 = i % (HWP / 4);
    int row = p4 / (WP / 4);              // 0..361
    int c4 = p4 % (WP / 4);               // 0..307
    float4 v = make_float4(0.f, 0.f, 0.f, 0.f);
    if (row >= PAD_T && row < PAD_T + HH && c4 >= 2 && c4 <= 305) {
        int y = row - PAD_T;
        int x0 = 4 * c4 - PAD_L;
        int idx = (b * HH + y) * WW + x0;  // 16B-aligned (x0 % 4 == 0)
        const float4 f = *(const float4*)(feat + idx);
        const float4 c = *(const float4*)(conf + idx);
        v = make_float4(f.x * c.x, f.y * c.y, f.z * c.z, f.w * c.w);
    }
    fc0[i] = v;
}

extern "C" void kernel_launch(void* const* d_in, const int* in_sizes, int n_in,
                              void* d_out, int out_size, void* d_ws, size_t ws_size,
                              hipStream_t stream)
{
    const float* feat_init  = (const float*)d_in[0];
    const float* guidance   = (const float*)d_in[1];
    const float* confidence = (const float*)d_in[2];
    const float* w_oa       = (const float*)d_in[3];
    const float* b_oa       = (const float*)d_in[4];
    const float* aff_scale  = (const float*)d_in[5];
    float* out = (float*)d_out;

    // Workspace: tab u32[12N] (82.2 MB) | fc0p f32[BB*HWP] | fc1p  (96.5 MB)
    const size_t N = (size_t)NPIX;
    unsigned* tab = (unsigned*)d_ws;
    float* fc0 = (float*)(tab + 12 * N);
    float* fc1 = fc0 + (size_t)BB * HWP;

    const int n4 = 2 * BB * HWP / 4;      // 891,968 float4 stores
    init_kernel<<<(n4 + 255) / 256, 256, 0, stream>>>(
        feat_init, confidence, (float4*)fc0, (float4*)fc1);
    conv_fused_kernel<<<2 * 1672, 256, 0, stream>>>(
        guidance, w_oa, b_oa, aff_scale, tab);

    const int pblocks = 1672;             // 2 tiles per block
    float* bufs[2] = {fc0, fc1};
    const int T = 18;
    for (int i = 0; i < T; ++i) {
        const float* src = bufs[i & 1];
        if (i < T - 1) {
            float* dst = bufs[(i + 1) & 1];
            prop_step_kernel<true><<<pblocks, 512, 0, stream>>>(
                src, tab, confidence, dst);
        } else {
            prop_step_kernel<false><<<pblocks, 512, 0, stream>>>(
                src, tab, confidence, out);
        }
    }
}